// Round 1
// baseline (200.831 us; speedup 1.0000x reference)
//
#include <hip/hip_runtime.h>

// L1Loss: per-(b,c) masked L1 sum / nonzero count, summed, / batch_size.
// B=16, C=64, H=128, W=128 -> 1024 (b,c) pairs x 16384 elements each.
// Memory-bound: 201 MB fp32 read -> ~32 us roofline at 6.3 TB/s.

#define HW_ELEMS 16384   // 128*128
#define HW_VEC4  4096    // HW_ELEMS / 4
#define NBC      1024    // B*C

__global__ __launch_bounds__(256) void l1_partial_kernel(
    const float* __restrict__ pre,
    const float* __restrict__ gt,
    const float* __restrict__ mask,
    float* __restrict__ ws) {
    const int bc = blockIdx.x;                  // 0..1023
    const size_t base = (size_t)bc * HW_ELEMS;
    const float4* __restrict__ p4 = (const float4*)(pre + base);
    const float4* __restrict__ g4 = (const float4*)(gt  + base);
    const float4* __restrict__ m4 = (const float4*)(mask + base);

    float s   = 0.0f;   // masked L1 partial
    float cnt = 0.0f;   // nonzero-count partial

    // 4096 float4 per (b,c); 256 threads -> 16 iterations, fully coalesced.
    for (int i = threadIdx.x; i < HW_VEC4; i += 256) {
        const float4 p = p4[i];
        const float4 g = g4[i];
        const float4 m = m4[i];
        s += fabsf(p.x - g.x) * m.x
           + fabsf(p.y - g.y) * m.y
           + fabsf(p.z - g.z) * m.z
           + fabsf(p.w - g.w) * m.w;
        cnt += (float)(m.x != 0.0f) + (float)(m.y != 0.0f)
             + (float)(m.z != 0.0f) + (float)(m.w != 0.0f);
    }

    // wave-64 butterfly reduce
    #pragma unroll
    for (int off = 32; off > 0; off >>= 1) {
        s   += __shfl_down(s,   off, 64);
        cnt += __shfl_down(cnt, off, 64);
    }

    __shared__ float ss[4];
    __shared__ float sc[4];
    const int wave = threadIdx.x >> 6;
    const int lane = threadIdx.x & 63;
    if (lane == 0) { ss[wave] = s; sc[wave] = cnt; }
    __syncthreads();
    if (threadIdx.x == 0) {
        const float S  = ss[0] + ss[1] + ss[2] + ss[3];
        const float Cn = sc[0] + sc[1] + sc[2] + sc[3];
        ws[bc] = S / fmaxf(Cn, 1.0f);
    }
}

__global__ __launch_bounds__(256) void l1_final_kernel(
    const float* __restrict__ ws,
    const int* __restrict__ bsz,
    float* __restrict__ out) {
    float s = 0.0f;
    for (int i = threadIdx.x; i < NBC; i += 256) s += ws[i];
    #pragma unroll
    for (int off = 32; off > 0; off >>= 1) s += __shfl_down(s, off, 64);
    __shared__ float ss[4];
    const int wave = threadIdx.x >> 6;
    const int lane = threadIdx.x & 63;
    if (lane == 0) ss[wave] = s;
    __syncthreads();
    if (threadIdx.x == 0) {
        out[0] = (ss[0] + ss[1] + ss[2] + ss[3]) / (float)bsz[0];
    }
}

extern "C" void kernel_launch(void* const* d_in, const int* in_sizes, int n_in,
                              void* d_out, int out_size, void* d_ws, size_t ws_size,
                              hipStream_t stream) {
    const float* pre  = (const float*)d_in[0];
    const float* gt   = (const float*)d_in[1];
    const float* mask = (const float*)d_in[2];
    const int*   bsz  = (const int*)d_in[3];
    float* ws  = (float*)d_ws;      // NBC floats of scratch (4 KB)
    float* out = (float*)d_out;

    l1_partial_kernel<<<NBC, 256, 0, stream>>>(pre, gt, mask, ws);
    l1_final_kernel<<<1, 256, 0, stream>>>(ws, bsz, out);
}

// Round 2
// 196.029 us; speedup vs baseline: 1.0245x; 1.0245x over previous
//
#include <hip/hip_runtime.h>

// L1Loss: per-(b,c) masked L1 sum / nonzero count, summed over (b,c), / batch.
// B=16, C=64, H=128, W=128 -> 1024 (b,c) pairs x 16384 elements.
// 201 MB fp32 inputs fit in 256 MiB L3 -> latency-bound, not HBM-bound.
// R1: split each (b,c) across SPLIT=4 blocks (4096 blocks total, 2x wave
// oversubscription) + batch all 12 float4 loads per thread before computing
// (12 outstanding loads/thread vs 3 in R0's rolled loop, VGPR 12 -> ~60).

#define NBC        1024          // B*C
#define SPLIT      4             // blocks per (b,c)
#define NBLK       (NBC * SPLIT) // 4096
#define VEC_PER_BLK 1024         // (128*128/4) float4 per block slice
#define VEC_PER_THR 4            // VEC_PER_BLK / 256

__global__ __launch_bounds__(256) void l1_partial_kernel(
    const float* __restrict__ pre,
    const float* __restrict__ gt,
    const float* __restrict__ mask,
    float* __restrict__ s_ws,
    float* __restrict__ c_ws) {
    const int blk = blockIdx.x;                       // 0..4095
    const size_t v4base = (size_t)blk * VEC_PER_BLK;  // float4 index
    const float4* __restrict__ p4 = (const float4*)pre  + v4base;
    const float4* __restrict__ g4 = (const float4*)gt   + v4base;
    const float4* __restrict__ m4 = (const float4*)mask + v4base;

    // Issue all 12 loads before any compute -> max MLP.
    float4 P[VEC_PER_THR], G[VEC_PER_THR], M[VEC_PER_THR];
    #pragma unroll
    for (int k = 0; k < VEC_PER_THR; ++k) {
        const int i = threadIdx.x + k * 256;
        P[k] = p4[i];
        G[k] = g4[i];
        M[k] = m4[i];
    }

    float s = 0.0f, cnt = 0.0f;
    #pragma unroll
    for (int k = 0; k < VEC_PER_THR; ++k) {
        s += fabsf(P[k].x - G[k].x) * M[k].x
           + fabsf(P[k].y - G[k].y) * M[k].y
           + fabsf(P[k].z - G[k].z) * M[k].z
           + fabsf(P[k].w - G[k].w) * M[k].w;
        cnt += (float)(M[k].x != 0.0f) + (float)(M[k].y != 0.0f)
             + (float)(M[k].z != 0.0f) + (float)(M[k].w != 0.0f);
    }

    // wave-64 butterfly reduce
    #pragma unroll
    for (int off = 32; off > 0; off >>= 1) {
        s   += __shfl_down(s,   off, 64);
        cnt += __shfl_down(cnt, off, 64);
    }

    __shared__ float ss[4];
    __shared__ float sc[4];
    const int wave = threadIdx.x >> 6;
    const int lane = threadIdx.x & 63;
    if (lane == 0) { ss[wave] = s; sc[wave] = cnt; }
    __syncthreads();
    if (threadIdx.x == 0) {
        s_ws[blk] = ss[0] + ss[1] + ss[2] + ss[3];
        c_ws[blk] = sc[0] + sc[1] + sc[2] + sc[3];
    }
}

// One block: fold SPLIT partials per (b,c), divide by clamped count,
// sum 1024 ratios, scale by 1/batch_size.
__global__ __launch_bounds__(256) void l1_final_kernel(
    const float* __restrict__ s_ws,
    const float* __restrict__ c_ws,
    const int* __restrict__ bsz,
    float* __restrict__ out) {
    float acc = 0.0f;
    #pragma unroll
    for (int j = 0; j < NBC / 256; ++j) {
        const int bc = threadIdx.x + j * 256;
        float S = 0.0f, Cn = 0.0f;
        #pragma unroll
        for (int h = 0; h < SPLIT; ++h) {
            S  += s_ws[bc * SPLIT + h];
            Cn += c_ws[bc * SPLIT + h];
        }
        acc += S / fmaxf(Cn, 1.0f);
    }
    #pragma unroll
    for (int off = 32; off > 0; off >>= 1) acc += __shfl_down(acc, off, 64);
    __shared__ float ss[4];
    const int wave = threadIdx.x >> 6;
    const int lane = threadIdx.x & 63;
    if (lane == 0) ss[wave] = acc;
    __syncthreads();
    if (threadIdx.x == 0) {
        out[0] = (ss[0] + ss[1] + ss[2] + ss[3]) / (float)bsz[0];
    }
}

extern "C" void kernel_launch(void* const* d_in, const int* in_sizes, int n_in,
                              void* d_out, int out_size, void* d_ws, size_t ws_size,
                              hipStream_t stream) {
    const float* pre  = (const float*)d_in[0];
    const float* gt   = (const float*)d_in[1];
    const float* mask = (const float*)d_in[2];
    const int*   bsz  = (const int*)d_in[3];
    float* s_ws = (float*)d_ws;          // NBLK floats
    float* c_ws = (float*)d_ws + NBLK;   // NBLK floats (32 KB total)
    float* out  = (float*)d_out;

    l1_partial_kernel<<<NBLK, 256, 0, stream>>>(pre, gt, mask, s_ws, c_ws);
    l1_final_kernel<<<1, 256, 0, stream>>>(s_ws, c_ws, bsz, out);
}

// Round 3
// 175.931 us; speedup vs baseline: 1.1415x; 1.1142x over previous
//
#include <hip/hip_runtime.h>

// L1Loss: per-(b,c) masked L1 sum / nonzero count, summed over (b,c), / batch.
// B=16, C=64, H=128, W=128 -> 1024 (b,c) pairs x 16384 elements, fp32.
// 201 MB read, latency/MLP-bound (L3-resident after harness restore).
// R2: force 12 outstanding loads/wave with sched_barrier(0) (R1's VGPR=28
// proved the compiler re-serialized the load batch) + nontemporal loads.

#define NBC        1024          // B*C
#define SPLIT      4             // blocks per (b,c)
#define NBLK       (NBC * SPLIT) // 4096
#define VEC_PER_BLK 1024         // (128*128/4) float4 per block slice
#define VEC_PER_THR 4            // VEC_PER_BLK / 256

typedef float v4f __attribute__((ext_vector_type(4)));

__global__ __launch_bounds__(256) void l1_partial_kernel(
    const float* __restrict__ pre,
    const float* __restrict__ gt,
    const float* __restrict__ mask,
    float* __restrict__ s_ws,
    float* __restrict__ c_ws) {
    const int blk = blockIdx.x;                       // 0..4095
    const size_t v4base = (size_t)blk * VEC_PER_BLK;  // float4 index
    const v4f* __restrict__ p4 = (const v4f*)pre  + v4base;
    const v4f* __restrict__ g4 = (const v4f*)gt   + v4base;
    const v4f* __restrict__ m4 = (const v4f*)mask + v4base;

    // Issue all 12 loads before any compute; fence stops the compiler from
    // interleaving compute (which re-serialized the loads in R1, VGPR=28).
    v4f P[VEC_PER_THR], G[VEC_PER_THR], M[VEC_PER_THR];
    #pragma unroll
    for (int k = 0; k < VEC_PER_THR; ++k) {
        const int i = threadIdx.x + k * 256;
        P[k] = __builtin_nontemporal_load(p4 + i);
        G[k] = __builtin_nontemporal_load(g4 + i);
        M[k] = __builtin_nontemporal_load(m4 + i);
    }
    __builtin_amdgcn_sched_barrier(0);   // no motion across: loads stay batched

    float s = 0.0f, cnt = 0.0f;
    #pragma unroll
    for (int k = 0; k < VEC_PER_THR; ++k) {
        s += fabsf(P[k].x - G[k].x) * M[k].x
           + fabsf(P[k].y - G[k].y) * M[k].y
           + fabsf(P[k].z - G[k].z) * M[k].z
           + fabsf(P[k].w - G[k].w) * M[k].w;
        cnt += (float)(M[k].x != 0.0f) + (float)(M[k].y != 0.0f)
             + (float)(M[k].z != 0.0f) + (float)(M[k].w != 0.0f);
    }

    // wave-64 butterfly reduce
    #pragma unroll
    for (int off = 32; off > 0; off >>= 1) {
        s   += __shfl_down(s,   off, 64);
        cnt += __shfl_down(cnt, off, 64);
    }

    __shared__ float ss[4];
    __shared__ float sc[4];
    const int wave = threadIdx.x >> 6;
    const int lane = threadIdx.x & 63;
    if (lane == 0) { ss[wave] = s; sc[wave] = cnt; }
    __syncthreads();
    if (threadIdx.x == 0) {
        s_ws[blk] = ss[0] + ss[1] + ss[2] + ss[3];
        c_ws[blk] = sc[0] + sc[1] + sc[2] + sc[3];
    }
}

// One block: fold SPLIT partials per (b,c), divide by clamped count,
// sum 1024 ratios, scale by 1/batch_size.
__global__ __launch_bounds__(256) void l1_final_kernel(
    const float* __restrict__ s_ws,
    const float* __restrict__ c_ws,
    const int* __restrict__ bsz,
    float* __restrict__ out) {
    float acc = 0.0f;
    #pragma unroll
    for (int j = 0; j < NBC / 256; ++j) {
        const int bc = threadIdx.x + j * 256;
        float S = 0.0f, Cn = 0.0f;
        #pragma unroll
        for (int h = 0; h < SPLIT; ++h) {
            S  += s_ws[bc * SPLIT + h];
            Cn += c_ws[bc * SPLIT + h];
        }
        acc += S / fmaxf(Cn, 1.0f);
    }
    #pragma unroll
    for (int off = 32; off > 0; off >>= 1) acc += __shfl_down(acc, off, 64);
    __shared__ float ss[4];
    const int wave = threadIdx.x >> 6;
    const int lane = threadIdx.x & 63;
    if (lane == 0) ss[wave] = acc;
    __syncthreads();
    if (threadIdx.x == 0) {
        out[0] = (ss[0] + ss[1] + ss[2] + ss[3]) / (float)bsz[0];
    }
}

extern "C" void kernel_launch(void* const* d_in, const int* in_sizes, int n_in,
                              void* d_out, int out_size, void* d_ws, size_t ws_size,
                              hipStream_t stream) {
    const float* pre  = (const float*)d_in[0];
    const float* gt   = (const float*)d_in[1];
    const float* mask = (const float*)d_in[2];
    const int*   bsz  = (const int*)d_in[3];
    float* s_ws = (float*)d_ws;          // NBLK floats
    float* c_ws = (float*)d_ws + NBLK;   // NBLK floats (32 KB total)
    float* out  = (float*)d_out;

    l1_partial_kernel<<<NBLK, 256, 0, stream>>>(pre, gt, mask, s_ws, c_ws);
    l1_final_kernel<<<1, 256, 0, stream>>>(s_ws, c_ws, bsz, out);
}